// Round 7
// baseline (317.253 us; speedup 1.0000x reference)
//
#include <hip/hip_runtime.h>
#include <math.h>

#define BB 2
#define SS 2048
#define DD 1024
#define HH 16
#define DKK 64
#define MM (BB * SS) /* 4096 */
#define KK DD        /* GEMM K = 1024 */

typedef __attribute__((ext_vector_type(8))) short short8;
typedef __attribute__((ext_vector_type(4))) float floatx4;

__device__ inline unsigned short f2bf(float x) {
    unsigned int u = __float_as_uint(x);
    u += 0x7fffu + ((u >> 16) & 1u);   // round to nearest even
    return (unsigned short)(u >> 16);
}

__device__ inline void cast4f(const float* __restrict__ in, unsigned short* __restrict__ out, int i) {
    const float4 v = *(const float4*)(in + i);
    unsigned long long pk = (unsigned long long)f2bf(v.x)
                          | ((unsigned long long)f2bf(v.y) << 16)
                          | ((unsigned long long)f2bf(v.z) << 32)
                          | ((unsigned long long)f2bf(v.w) << 48);
    *(unsigned long long*)(out + i) = pk;
}

__global__ __launch_bounds__(256) void cast3(const float* __restrict__ a, const float* __restrict__ b,
                                             const float* __restrict__ c,
                                             unsigned short* __restrict__ oa, unsigned short* __restrict__ ob,
                                             unsigned short* __restrict__ oc) {
    const int w = blockIdx.y;
    const float* in = (w == 0) ? a : (w == 1) ? b : c;
    unsigned short* out = (w == 0) ? oa : (w == 1) ? ob : oc;
    cast4f(in, out, (blockIdx.x * 256 + threadIdx.x) * 4);
}

__global__ __launch_bounds__(256) void cast4w(const float* __restrict__ a, const float* __restrict__ b,
                                              const float* __restrict__ c, const float* __restrict__ d,
                                              unsigned short* __restrict__ oa, unsigned short* __restrict__ ob,
                                              unsigned short* __restrict__ oc, unsigned short* __restrict__ od) {
    const int w = blockIdx.y;
    const float* in = (w == 0) ? a : (w == 1) ? b : (w == 2) ? c : d;
    unsigned short* out = (w == 0) ? oa : (w == 1) ? ob : (w == 2) ? oc : od;
    cast4f(in, out, (blockIdx.x * 256 + threadIdx.x) * 4);
}

#define GLDS(gp, lp) __builtin_amdgcn_global_load_lds( \
    (const __attribute__((address_space(1))) void*)(gp), \
    (__attribute__((address_space(3))) void*)(lp), 16, 0, 0)

// 64(M)x128(N) tile, BK=32, dbuf LDS, XOR-swizzled k-segments.
__device__ __forceinline__ void gemm_body(const unsigned short* __restrict__ A,
                                          const unsigned short* __restrict__ W,
                                          const float* __restrict__ bias,
                                          void* __restrict__ Cout, int mode, int blk,
                                          unsigned short* As, unsigned short* Bs) {
    const int t    = threadIdx.x;
    const int lane = t & 63;
    const int wave = t >> 6;
    const int col  = lane & 15;
    const int quad = lane >> 4;

    const int m0  = (blk & 63) * 64;
    const int n0  = (blk >> 6) * 128;
    const int wm0 = (wave & 1) * 32;
    const int wn0 = (wave >> 1) * 64;

    const int sw = ((t & 3) ^ ((t >> 3) & 3)) * 8;
    const size_t arow = (size_t)(m0 + (t >> 2)) * KK + sw;
    const size_t brow = (size_t)(n0 + (t >> 2)) * KK + sw;
    const int rseg = (quad ^ ((col >> 1) & 3)) * 8;

    floatx4 acc[2][4] = {};

    GLDS(A + arow,           &As[(t >> 2) * 32 + sw]);
    GLDS(W + brow,           &Bs[(t >> 2) * 32 + sw]);
    GLDS(W + brow + 64 * KK, &Bs[(64 + (t >> 2)) * 32 + sw]);

    int cur = 0;
    for (int kb = 0; kb < KK / 32; ++kb) {
        __syncthreads();

        if (kb + 1 < KK / 32) {
            const int k0 = (kb + 1) * 32;
            const int nx = cur ^ 1;
            GLDS(A + arow + k0,           &As[nx * 64 * 32 + (t >> 2) * 32 + sw]);
            GLDS(W + brow + k0,           &Bs[nx * 128 * 32 + (t >> 2) * 32 + sw]);
            GLDS(W + brow + k0 + 64 * KK, &Bs[nx * 128 * 32 + (64 + (t >> 2)) * 32 + sw]);
        }

        const unsigned short* Ab = &As[cur * 64 * 32];
        const unsigned short* Bb = &Bs[cur * 128 * 32];
        short8 a[2], b[4];
        #pragma unroll
        for (int i = 0; i < 2; ++i)
            a[i] = *(const short8*)(Ab + (wm0 + i * 16 + col) * 32 + rseg);
        #pragma unroll
        for (int j = 0; j < 4; ++j)
            b[j] = *(const short8*)(Bb + (wn0 + j * 16 + col) * 32 + rseg);

        #pragma unroll
        for (int i = 0; i < 2; ++i)
            #pragma unroll
            for (int j = 0; j < 4; ++j)
                acc[i][j] = __builtin_amdgcn_mfma_f32_16x16x32_bf16(a[i], b[j], acc[i][j], 0, 0, 0);

        cur ^= 1;
    }

    #pragma unroll
    for (int i = 0; i < 2; ++i) {
        #pragma unroll
        for (int j = 0; j < 4; ++j) {
            const int n  = n0 + wn0 + j * 16 + col;
            const float bv = bias[n];
            const int h = n / DKK, dk = n % DKK;
            #pragma unroll
            for (int r = 0; r < 4; ++r) {
                const int m = m0 + wm0 + i * 16 + quad * 4 + r;
                const int bdx = m / SS, s = m % SS;
                const float v = acc[i][j][r] + bv;
                if (mode == 0) {
                    ((unsigned short*)Cout)[(((size_t)(bdx * HH + h)) * SS + s) * DKK + dk] = f2bf(v);
                } else if (mode == 1) {
                    ((unsigned short*)Cout)[(((size_t)(bdx * HH + h)) * DKK + dk) * SS + s] = f2bf(v);
                } else {
                    ((float*)Cout)[(size_t)m * DD + n] = v;
                }
            }
        }
    }
}

// fused Q/K/V projections: 1536 blocks (3 x 512) -> 6 blocks/CU overlap
__global__ __launch_bounds__(256) void gemm_qkv(const unsigned short* __restrict__ qB,
                                                const unsigned short* __restrict__ kB,
                                                const unsigned short* __restrict__ vB,
                                                const unsigned short* __restrict__ wqB,
                                                const unsigned short* __restrict__ wkB,
                                                const unsigned short* __restrict__ wvB,
                                                const float* __restrict__ bq,
                                                const float* __restrict__ bk,
                                                const float* __restrict__ bv,
                                                unsigned short* __restrict__ Qh,
                                                unsigned short* __restrict__ Kh,
                                                unsigned short* __restrict__ Vt) {
    __shared__ __align__(16) unsigned short As[2 * 64 * 32];
    __shared__ __align__(16) unsigned short Bs[2 * 128 * 32];
    const int which = blockIdx.x >> 9;
    const int blk   = blockIdx.x & 511;
    if (which == 0)      gemm_body(qB, wqB, bq, Qh, 0, blk, As, Bs);
    else if (which == 1) gemm_body(kB, wkB, bk, Kh, 0, blk, As, Bs);
    else                 gemm_body(vB, wvB, bv, Vt, 1, blk, As, Bs);
}

__global__ __launch_bounds__(256) void gemm_out(const unsigned short* __restrict__ A,
                                                const unsigned short* __restrict__ W,
                                                const float* __restrict__ bias,
                                                float* __restrict__ C) {
    __shared__ __align__(16) unsigned short As[2 * 64 * 32];
    __shared__ __align__(16) unsigned short Bs[2 * 128 * 32];
    gemm_body(A, W, bias, C, 2, blockIdx.x, As, Bs);
}

// ---- attention ----
#define C1 0.18033688011112042f   /* 0.125 * log2(e) */
#define C2 11.541560327111707f    /* 8 * log2(e)     */

#define MFMA __builtin_amdgcn_mfma_f32_16x16x32_bf16

#define LOADK(kk, jj)                                                           \
    {                                                                           \
        const unsigned short* Kp = Kb + (size_t)((jj) + col) * DKK + quad * 8;  \
        kk##0 = *(const short8*)(Kp);                                           \
        kk##1 = *(const short8*)(Kp + 32);                                      \
        kk##2 = *(const short8*)(Kp + 16 * DKK);                                \
        kk##3 = *(const short8*)(Kp + 16 * DKK + 32);                           \
    }

#define LOADV(vv, jj)                                                           \
    {                                                                           \
        const unsigned short* Vp = Vb + (jj) + quad * 8;                        \
        vv##0 = *(const short8*)(Vp + (size_t)(col)      * SS);                 \
        vv##1 = *(const short8*)(Vp + (size_t)(16 + col) * SS);                 \
        vv##2 = *(const short8*)(Vp + (size_t)(32 + col) * SS);                 \
        vv##3 = *(const short8*)(Vp + (size_t)(48 + col) * SS);                 \
    }

#define QK4(sd0, sd1, kk)                       \
    {                                           \
        sd0 = (floatx4){0.f, 0.f, 0.f, 0.f};    \
        sd1 = (floatx4){0.f, 0.f, 0.f, 0.f};    \
        sd0 = MFMA(qa0, kk##0, sd0, 0, 0, 0);   \
        sd0 = MFMA(qa1, kk##1, sd0, 0, 0, 0);   \
        sd1 = MFMA(qa0, kk##2, sd1, 0, 0, 0);   \
        sd1 = MFMA(qa1, kk##3, sd1, 0, 0, 0);   \
    }

// exp + P->LDS (truncating bf16) + pa read + PV accumulate
#define SOFTPV(j0v, vv)                                                                              \
    {                                                                                                \
        if ((j0v) + 31 > q0) {                                                                       \
            _Pragma("unroll")                                                                        \
            for (int r = 0; r < 4; ++r) {                                                            \
                const int row = q0 + quad * 4 + r;                                                   \
                const float p0 = ((j0v) + col      <= row) ? __builtin_exp2f(fmaf(sc0[r], C1, -C2)) : 0.f; \
                const float p1 = ((j0v) + 16 + col <= row) ? __builtin_exp2f(fmaf(sc1[r], C1, -C2)) : 0.f; \
                lp[r] += p0 + p1;                                                                    \
                Pw[(quad * 4 + r) * 40 + col]      = (unsigned short)(__float_as_uint(p0) >> 16);    \
                Pw[(quad * 4 + r) * 40 + col + 16] = (unsigned short)(__float_as_uint(p1) >> 16);    \
            }                                                                                        \
        } else {                                                                                     \
            _Pragma("unroll")                                                                        \
            for (int r = 0; r < 4; ++r) {                                                            \
                const float p0 = __builtin_exp2f(fmaf(sc0[r], C1, -C2));                             \
                const float p1 = __builtin_exp2f(fmaf(sc1[r], C1, -C2));                             \
                lp[r] += p0 + p1;                                                                    \
                Pw[(quad * 4 + r) * 40 + col]      = (unsigned short)(__float_as_uint(p0) >> 16);    \
                Pw[(quad * 4 + r) * 40 + col + 16] = (unsigned short)(__float_as_uint(p1) >> 16);    \
            }                                                                                        \
        }                                                                                            \
        const short8 pa = *(const short8*)(Pw + col * 40 + quad * 8);                                \
        o0 = MFMA(pa, vv##0, o0, 0, 0, 0);                                                           \
        o1 = MFMA(pa, vv##1, o1, 0, 0, 0);                                                           \
        o2 = MFMA(pa, vv##2, o2, 0, 0, 0);                                                           \
        o3 = MFMA(pa, vv##3, o3, 0, 0, 0);                                                           \
    }

// Split-K flash attention: one block per (head, 16-query tile); the tile's key
// blocks are split ~equally across the 4 waves (fixed-shift softmax => partial
// (o,l) combine by plain addition in an LDS reduction). 4096 blocks, balanced.
__global__ __launch_bounds__(256) void attn_mfma(const unsigned short* __restrict__ Qh,
                                                 const unsigned short* __restrict__ Kh,
                                                 const unsigned short* __restrict__ Vt,
                                                 unsigned short* __restrict__ X) {
    __shared__ unsigned short Plds[4][16 * 40];
    __shared__ float redO[4][16 * 64];
    __shared__ float redL[4][16];

    const int t    = threadIdx.x;
    const int lane = t & 63;
    const int wave = t >> 6;
    const int col  = lane & 15;
    const int quad = lane >> 4;

    const int lin = blockIdx.x;           // 0..4095
    const int xcd = lin & 7;
    const int rem = lin >> 3;             // 0..511
    const int bh  = xcd + 8 * (rem & 3);  // heads {x,x+8,x+16,x+24} on xcd x
    const int tile = rem >> 2;            // 0..127
    const int q0 = tile * 16;
    const int b  = bh / HH, h = bh % HH;

    unsigned short* Pw = &Plds[wave][0];
    const unsigned short* Kb = Kh + (size_t)bh * SS * DKK;
    const unsigned short* Vb = Vt + (size_t)bh * DKK * SS;

    const unsigned short* Qb = Qh + ((size_t)bh * SS + q0) * DKK;
    const short8 qa0 = *(const short8*)(Qb + (size_t)col * DKK + quad * 8);
    const short8 qa1 = *(const short8*)(Qb + (size_t)col * DKK + 32 + quad * 8);

    floatx4 o0 = {0.f, 0.f, 0.f, 0.f}, o1 = o0, o2 = o0, o3 = o0;
    float lp[4] = {0.f, 0.f, 0.f, 0.f};

    const int nkb = (16 * tile + 47) / 32;     // total key blocks for this tile
    const int cpw = (nkb + 3) >> 2;            // blocks per wave (ceil)
    const int lo  = wave * cpw;
    const int hi  = (nkb < lo + cpw) ? nkb : lo + cpw;

    if (lo < hi) {
        short8 kA0, kA1, kA2, kA3, kB0, kB1, kB2, kB3;
        short8 vA0, vA1, vA2, vA3, vB0, vB1, vB2, vB3;
        floatx4 sc0, sc1, sn0, sn1;

        LOADK(kA, lo * 32)
        LOADV(vA, lo * 32)
        if (lo + 1 < hi) LOADK(kB, lo * 32 + 32)
        QK4(sc0, sc1, kA)

        for (int jb = lo; jb < hi; jb += 2) {
            const int j0 = jb * 32;
            // even body: current block jb (V in vA); next K in kB
            if (jb + 1 < hi) QK4(sn0, sn1, kB)
            if (jb + 2 < hi) LOADK(kA, j0 + 64)
            if (jb + 1 < hi) LOADV(vB, j0 + 32)
            SOFTPV(j0, vA)
            sc0 = sn0; sc1 = sn1;
            if (jb + 1 >= hi) break;
            // odd body: current block jb+1 (V in vB); next K in kA
            if (jb + 2 < hi) QK4(sn0, sn1, kA)
            if (jb + 3 < hi) LOADK(kB, j0 + 96)
            if (jb + 2 < hi) LOADV(vA, j0 + 64)
            SOFTPV(j0 + 32, vB)
            sc0 = sn0; sc1 = sn1;
        }
    }

    // wave-local row sums of l (over this wave's 16 score columns)
    #pragma unroll
    for (int r = 0; r < 4; ++r) {
        float s = lp[r];
        s += __shfl_xor(s, 1, 64);
        s += __shfl_xor(s, 2, 64);
        s += __shfl_xor(s, 4, 64);
        s += __shfl_xor(s, 8, 64);
        if (col == 0) redL[wave][quad * 4 + r] = s;
    }

    // stash o partials
    #pragma unroll
    for (int r = 0; r < 4; ++r) {
        redO[wave][(quad * 4 + r) * 64 + col]      = o0[r];
        redO[wave][(quad * 4 + r) * 64 + col + 16] = o1[r];
        redO[wave][(quad * 4 + r) * 64 + col + 32] = o2[r];
        redO[wave][(quad * 4 + r) * 64 + col + 48] = o3[r];
    }
    __syncthreads();

    // combine 4 wave partials; 256 threads cover the 16x64 output tile
    const int row = t >> 4;        // 0..15
    const int c0  = t & 15;        // 0..15
    const float li = 1.f / (redL[0][row] + redL[1][row] + redL[2][row] + redL[3][row]);
    unsigned short* Xp = X + ((size_t)(b * SS + q0 + row)) * DD + h * DKK + c0;
    #pragma unroll
    for (int j = 0; j < 4; ++j) {
        const int c64 = j * 16 + c0;
        const float s = redO[0][row * 64 + c64] + redO[1][row * 64 + c64]
                      + redO[2][row * 64 + c64] + redO[3][row * 64 + c64];
        Xp[j * 16] = f2bf(s * li);
    }
}

extern "C" void kernel_launch(void* const* d_in, const int* in_sizes, int n_in,
                              void* d_out, int out_size, void* d_ws, size_t ws_size,
                              hipStream_t stream) {
    const float* query = (const float*)d_in[0];
    const float* key   = (const float*)d_in[1];
    const float* value = (const float*)d_in[2];
    const float* wq    = (const float*)d_in[3];
    const float* bq    = (const float*)d_in[4];
    const float* wk    = (const float*)d_in[5];
    const float* bk    = (const float*)d_in[6];
    const float* wv    = (const float*)d_in[7];
    const float* bv    = (const float*)d_in[8];
    const float* wo    = (const float*)d_in[9];
    const float* bo    = (const float*)d_in[10];

    char* ws = (char*)d_ws;
    const size_t MB = 1024 * 1024;
    unsigned short* qB  = (unsigned short*)(ws);             // bf16 [4096,1024] 8 MB
    unsigned short* kB  = (unsigned short*)(ws + 8 * MB);
    unsigned short* vB  = (unsigned short*)(ws + 16 * MB);
    unsigned short* wqB = (unsigned short*)(ws + 24 * MB);   // bf16 [1024,1024] 2 MB
    unsigned short* wkB = (unsigned short*)(ws + 26 * MB);
    unsigned short* wvB = (unsigned short*)(ws + 28 * MB);
    unsigned short* woB = (unsigned short*)(ws + 30 * MB);
    unsigned short* Qh  = (unsigned short*)(ws + 32 * MB);   // bf16 [B,H,S,DK] 8 MB
    unsigned short* Kh  = (unsigned short*)(ws + 40 * MB);
    unsigned short* Vt  = (unsigned short*)(ws + 48 * MB);   // bf16 [B,H,DK,S] 8 MB
    unsigned short* Xb  = (unsigned short*)(ws + 56 * MB);   // bf16 [B,S,D]    8 MB

    cast3<<<dim3(4096, 3), 256, 0, stream>>>(query, key, value, qB, kB, vB);
    cast4w<<<dim3(1024, 4), 256, 0, stream>>>(wq, wk, wv, wo, wqB, wkB, wvB, woB);

    gemm_qkv<<<1536, 256, 0, stream>>>(qB, kB, vB, wqB, wkB, wvB, bq, bk, bv, Qh, Kh, Vt);

    attn_mfma<<<4096, 256, 0, stream>>>(Qh, Kh, Vt, Xb);

    gemm_out<<<512, 256, 0, stream>>>(Xb, woB, bo, (float*)d_out);
}

// Round 8
// 250.278 us; speedup vs baseline: 1.2676x; 1.2676x over previous
//
#include <hip/hip_runtime.h>
#include <math.h>

#define BB 2
#define SS 2048
#define DD 1024
#define HH 16
#define DKK 64
#define MM (BB * SS) /* 4096 */
#define KK DD        /* GEMM K = 1024 */
#define VSTR 2176    /* Vt row stride in shorts (4352 B) — breaks 4 KB channel aliasing */

typedef __attribute__((ext_vector_type(8))) short short8;
typedef __attribute__((ext_vector_type(4))) float floatx4;

__device__ inline unsigned short f2bf(float x) {
    unsigned int u = __float_as_uint(x);
    u += 0x7fffu + ((u >> 16) & 1u);   // round to nearest even
    return (unsigned short)(u >> 16);
}

__device__ inline void cast4f(const float* __restrict__ in, unsigned short* __restrict__ out, int i) {
    const float4 v = *(const float4*)(in + i);
    unsigned long long pk = (unsigned long long)f2bf(v.x)
                          | ((unsigned long long)f2bf(v.y) << 16)
                          | ((unsigned long long)f2bf(v.z) << 32)
                          | ((unsigned long long)f2bf(v.w) << 48);
    *(unsigned long long*)(out + i) = pk;
}

__global__ __launch_bounds__(256) void cast3(const float* __restrict__ a, const float* __restrict__ b,
                                             const float* __restrict__ c,
                                             unsigned short* __restrict__ oa, unsigned short* __restrict__ ob,
                                             unsigned short* __restrict__ oc) {
    const int w = blockIdx.y;
    const float* in = (w == 0) ? a : (w == 1) ? b : c;
    unsigned short* out = (w == 0) ? oa : (w == 1) ? ob : oc;
    cast4f(in, out, (blockIdx.x * 256 + threadIdx.x) * 4);
}

__global__ __launch_bounds__(256) void cast4w(const float* __restrict__ a, const float* __restrict__ b,
                                              const float* __restrict__ c, const float* __restrict__ d,
                                              unsigned short* __restrict__ oa, unsigned short* __restrict__ ob,
                                              unsigned short* __restrict__ oc, unsigned short* __restrict__ od) {
    const int w = blockIdx.y;
    const float* in = (w == 0) ? a : (w == 1) ? b : (w == 2) ? c : d;
    unsigned short* out = (w == 0) ? oa : (w == 1) ? ob : (w == 2) ? oc : od;
    cast4f(in, out, (blockIdx.x * 256 + threadIdx.x) * 4);
}

#define GLDS(gp, lp) __builtin_amdgcn_global_load_lds( \
    (const __attribute__((address_space(1))) void*)(gp), \
    (__attribute__((address_space(3))) void*)(lp), 16, 0, 0)

// 64(M)x128(N) tile, BK=32, dbuf LDS, XOR-swizzled k-segments.
__device__ __forceinline__ void gemm_body(const unsigned short* __restrict__ A,
                                          const unsigned short* __restrict__ W,
                                          const float* __restrict__ bias,
                                          void* __restrict__ Cout, int mode, int blk,
                                          unsigned short* As, unsigned short* Bs) {
    const int t    = threadIdx.x;
    const int lane = t & 63;
    const int wave = t >> 6;
    const int col  = lane & 15;
    const int quad = lane >> 4;

    const int m0  = (blk & 63) * 64;
    const int n0  = (blk >> 6) * 128;
    const int wm0 = (wave & 1) * 32;
    const int wn0 = (wave >> 1) * 64;

    const int sw = ((t & 3) ^ ((t >> 3) & 3)) * 8;
    const size_t arow = (size_t)(m0 + (t >> 2)) * KK + sw;
    const size_t brow = (size_t)(n0 + (t >> 2)) * KK + sw;
    const int rseg = (quad ^ ((col >> 1) & 3)) * 8;

    floatx4 acc[2][4] = {};

    GLDS(A + arow,           &As[(t >> 2) * 32 + sw]);
    GLDS(W + brow,           &Bs[(t >> 2) * 32 + sw]);
    GLDS(W + brow + 64 * KK, &Bs[(64 + (t >> 2)) * 32 + sw]);

    int cur = 0;
    for (int kb = 0; kb < KK / 32; ++kb) {
        __syncthreads();

        if (kb + 1 < KK / 32) {
            const int k0 = (kb + 1) * 32;
            const int nx = cur ^ 1;
            GLDS(A + arow + k0,           &As[nx * 64 * 32 + (t >> 2) * 32 + sw]);
            GLDS(W + brow + k0,           &Bs[nx * 128 * 32 + (t >> 2) * 32 + sw]);
            GLDS(W + brow + k0 + 64 * KK, &Bs[nx * 128 * 32 + (64 + (t >> 2)) * 32 + sw]);
        }

        const unsigned short* Ab = &As[cur * 64 * 32];
        const unsigned short* Bb = &Bs[cur * 128 * 32];
        short8 a[2], b[4];
        #pragma unroll
        for (int i = 0; i < 2; ++i)
            a[i] = *(const short8*)(Ab + (wm0 + i * 16 + col) * 32 + rseg);
        #pragma unroll
        for (int j = 0; j < 4; ++j)
            b[j] = *(const short8*)(Bb + (wn0 + j * 16 + col) * 32 + rseg);

        #pragma unroll
        for (int i = 0; i < 2; ++i)
            #pragma unroll
            for (int j = 0; j < 4; ++j)
                acc[i][j] = __builtin_amdgcn_mfma_f32_16x16x32_bf16(a[i], b[j], acc[i][j], 0, 0, 0);

        cur ^= 1;
    }

    #pragma unroll
    for (int i = 0; i < 2; ++i) {
        #pragma unroll
        for (int j = 0; j < 4; ++j) {
            const int n  = n0 + wn0 + j * 16 + col;
            const float bv = bias[n];
            const int h = n / DKK, dk = n % DKK;
            #pragma unroll
            for (int r = 0; r < 4; ++r) {
                const int m = m0 + wm0 + i * 16 + quad * 4 + r;
                const int bdx = m / SS, s = m % SS;
                const float v = acc[i][j][r] + bv;
                if (mode == 0) {
                    ((unsigned short*)Cout)[(((size_t)(bdx * HH + h)) * SS + s) * DKK + dk] = f2bf(v);
                } else if (mode == 1) {
                    ((unsigned short*)Cout)[(((size_t)(bdx * HH + h)) * DKK + dk) * VSTR + s] = f2bf(v);
                } else {
                    ((float*)Cout)[(size_t)m * DD + n] = v;
                }
            }
        }
    }
}

// fused Q/K/V projections: 1536 blocks (3 x 512) -> 6 blocks/CU overlap
__global__ __launch_bounds__(256) void gemm_qkv(const unsigned short* __restrict__ qB,
                                                const unsigned short* __restrict__ kB,
                                                const unsigned short* __restrict__ vB,
                                                const unsigned short* __restrict__ wqB,
                                                const unsigned short* __restrict__ wkB,
                                                const unsigned short* __restrict__ wvB,
                                                const float* __restrict__ bq,
                                                const float* __restrict__ bk,
                                                const float* __restrict__ bv,
                                                unsigned short* __restrict__ Qh,
                                                unsigned short* __restrict__ Kh,
                                                unsigned short* __restrict__ Vt) {
    __shared__ __align__(16) unsigned short As[2 * 64 * 32];
    __shared__ __align__(16) unsigned short Bs[2 * 128 * 32];
    const int which = blockIdx.x >> 9;
    const int blk   = blockIdx.x & 511;
    if (which == 0)      gemm_body(qB, wqB, bq, Qh, 0, blk, As, Bs);
    else if (which == 1) gemm_body(kB, wkB, bk, Kh, 0, blk, As, Bs);
    else                 gemm_body(vB, wvB, bv, Vt, 1, blk, As, Bs);
}

__global__ __launch_bounds__(256) void gemm_out(const unsigned short* __restrict__ A,
                                                const unsigned short* __restrict__ W,
                                                const float* __restrict__ bias,
                                                float* __restrict__ C) {
    __shared__ __align__(16) unsigned short As[2 * 64 * 32];
    __shared__ __align__(16) unsigned short Bs[2 * 128 * 32];
    gemm_body(A, W, bias, C, 2, blockIdx.x, As, Bs);
}

// ---- attention ----
#define C1 0.18033688011112042f   /* 0.125 * log2(e) */
#define C2 11.541560327111707f    /* 8 * log2(e)     */

#define MFMA __builtin_amdgcn_mfma_f32_16x16x32_bf16

// exp + P->LDS (truncating bf16) + pa read + PV accumulate
#define SOFTPV(j0v, vv)                                                                              \
    {                                                                                                \
        if ((j0v) + 31 > q0) {                                                                       \
            _Pragma("unroll")                                                                        \
            for (int r = 0; r < 4; ++r) {                                                            \
                const int row = q0 + quad * 4 + r;                                                   \
                const float p0 = ((j0v) + col      <= row) ? __builtin_exp2f(fmaf(sc0[r], C1, -C2)) : 0.f; \
                const float p1 = ((j0v) + 16 + col <= row) ? __builtin_exp2f(fmaf(sc1[r], C1, -C2)) : 0.f; \
                lp[r] += p0 + p1;                                                                    \
                Pw[(quad * 4 + r) * 40 + col]      = (unsigned short)(__float_as_uint(p0) >> 16);    \
                Pw[(quad * 4 + r) * 40 + col + 16] = (unsigned short)(__float_as_uint(p1) >> 16);    \
            }                                                                                        \
        } else {                                                                                     \
            _Pragma("unroll")                                                                        \
            for (int r = 0; r < 4; ++r) {                                                            \
                const float p0 = __builtin_exp2f(fmaf(sc0[r], C1, -C2));                             \
                const float p1 = __builtin_exp2f(fmaf(sc1[r], C1, -C2));                             \
                lp[r] += p0 + p1;                                                                    \
                Pw[(quad * 4 + r) * 40 + col]      = (unsigned short)(__float_as_uint(p0) >> 16);    \
                Pw[(quad * 4 + r) * 40 + col + 16] = (unsigned short)(__float_as_uint(p1) >> 16);    \
            }                                                                                        \
        }                                                                                            \
        const short8 pa = *(const short8*)(Pw + col * 40 + quad * 8);                                \
        o0 = MFMA(pa, vv##0, o0, 0, 0, 0);                                                           \
        o1 = MFMA(pa, vv##1, o1, 0, 0, 0);                                                           \
        o2 = MFMA(pa, vv##2, o2, 0, 0, 0);                                                           \
        o3 = MFMA(pa, vv##3, o3, 0, 0, 0);                                                           \
    }

// GEMM-style flash attention: one block = 64 consecutive queries (4 waves x 16),
// K/V tiles staged block-wide into dbuf LDS via global_load_lds (4x traffic cut),
// same barrier structure as gemm_body. K segs XOR-swizzled for b128 reads.
__global__ __launch_bounds__(256) void attn_mfma(const unsigned short* __restrict__ Qh,
                                                 const unsigned short* __restrict__ Kh,
                                                 const unsigned short* __restrict__ Vt,
                                                 unsigned short* __restrict__ X) {
    __shared__ __align__(16) unsigned short Ks[2][32 * 64];  // [key][dim], swizzled segs
    __shared__ __align__(16) unsigned short Vs[2][64 * 32];  // [dim][key]
    __shared__ unsigned short Plds[4][16 * 40];

    const int t    = threadIdx.x;
    const int lane = t & 63;
    const int wave = t >> 6;
    const int col  = lane & 15;
    const int quad = lane >> 4;

    // lin -> xcd = lin&7 (heads {x,x+8,x+16,x+24} per xcd); chunk descending (longest first)
    const int lin = blockIdx.x;                    // 0..1023
    const int bh  = (lin & 7) + 8 * ((lin >> 3) & 3);
    const int c   = 31 - (lin >> 5);               // 0..31, chunk of 64 queries
    const int b   = bh / HH, h = bh % HH;

    const unsigned short* Kb = Kh + (size_t)bh * SS * DKK;
    const unsigned short* Vb = Vt + (size_t)bh * DKK * VSTR;

    // staging source offsets (thread-invariant)
    const int kRow = t >> 3;                       // key row 0..31 (128 B each)
    const int kSeg = ((t & 7) ^ (kRow & 7)) * 8;   // XOR-swizzled 16B seg
    const int vRow = t >> 2;                       // dim row 0..63 (64 B each)
    const int vSeg = (t & 3) * 8;

    // wave's query tile
    const int q0 = c * 64 + wave * 16;
    unsigned short* Pw = &Plds[wave][0];

    const unsigned short* Qb = Qh + ((size_t)bh * SS + q0) * DKK;
    const short8 qa0 = *(const short8*)(Qb + (size_t)col * DKK + quad * 8);
    const short8 qa1 = *(const short8*)(Qb + (size_t)col * DKK + 32 + quad * 8);

    floatx4 o0 = {0.f, 0.f, 0.f, 0.f}, o1 = o0, o2 = o0, o3 = o0;
    float lp[4] = {0.f, 0.f, 0.f, 0.f};

    const int nkb = 2 * (c + 1);                   // 32-key steps for this block

    // K frag read offsets (XOR swizzle must match staging)
    const int ks0 = ((quad     ^ (col & 7)) << 3);
    const int ks1 = (((quad|4) ^ (col & 7)) << 3);

    // prologue: stage step 0 into buf 0
    GLDS(Kb + (size_t)kRow * DKK + kSeg, &Ks[0][t * 8]);
    GLDS(Vb + (size_t)vRow * VSTR + vSeg, &Vs[0][t * 8]);

    int cur = 0;
    for (int kb = 0; kb < nkb; ++kb) {
        __syncthreads();   // staging(cur) done; buf cur^1 reads from prev iter done

        if (kb + 1 < nkb) {
            const int jn = (kb + 1) * 32;
            const int nx = cur ^ 1;
            GLDS(Kb + (size_t)(jn + kRow) * DKK + kSeg, &Ks[nx][t * 8]);
            GLDS(Vb + (size_t)vRow * VSTR + jn + vSeg, &Vs[nx][t * 8]);
        }

        const int j0 = kb * 32;
        if (j0 < q0 + 16) {   // wave-active (causal)
            const unsigned short* Kp = &Ks[cur][0];
            const short8 k0 = *(const short8*)(Kp + col * 64 + ks0);
            const short8 k1 = *(const short8*)(Kp + col * 64 + ks1);
            const short8 k2 = *(const short8*)(Kp + (col + 16) * 64 + ks0);
            const short8 k3 = *(const short8*)(Kp + (col + 16) * 64 + ks1);

            floatx4 sc0 = {0.f, 0.f, 0.f, 0.f}, sc1 = sc0;
            sc0 = MFMA(qa0, k0, sc0, 0, 0, 0);
            sc0 = MFMA(qa1, k1, sc0, 0, 0, 0);
            sc1 = MFMA(qa0, k2, sc1, 0, 0, 0);
            sc1 = MFMA(qa1, k3, sc1, 0, 0, 0);

            const unsigned short* Vp = &Vs[cur][0];
            short8 vv0 = *(const short8*)(Vp + (col)      * 32 + quad * 8);
            short8 vv1 = *(const short8*)(Vp + (col + 16) * 32 + quad * 8);
            short8 vv2 = *(const short8*)(Vp + (col + 32) * 32 + quad * 8);
            short8 vv3 = *(const short8*)(Vp + (col + 48) * 32 + quad * 8);

            SOFTPV(j0, vv)
        }

        cur ^= 1;
    }

    #pragma unroll
    for (int r = 0; r < 4; ++r) {
        float s = lp[r];
        s += __shfl_xor(s, 1, 64);
        s += __shfl_xor(s, 2, 64);
        s += __shfl_xor(s, 4, 64);
        s += __shfl_xor(s, 8, 64);
        lp[r] = 1.f / s;
    }

    unsigned short* Xp = X + ((size_t)(b * SS + q0 + quad * 4)) * DD + h * DKK + col;
    #pragma unroll
    for (int r = 0; r < 4; ++r) {
        Xp[(size_t)r * DD + 0]  = f2bf(o0[r] * lp[r]);
        Xp[(size_t)r * DD + 16] = f2bf(o1[r] * lp[r]);
        Xp[(size_t)r * DD + 32] = f2bf(o2[r] * lp[r]);
        Xp[(size_t)r * DD + 48] = f2bf(o3[r] * lp[r]);
    }
}

extern "C" void kernel_launch(void* const* d_in, const int* in_sizes, int n_in,
                              void* d_out, int out_size, void* d_ws, size_t ws_size,
                              hipStream_t stream) {
    const float* query = (const float*)d_in[0];
    const float* key   = (const float*)d_in[1];
    const float* value = (const float*)d_in[2];
    const float* wq    = (const float*)d_in[3];
    const float* bq    = (const float*)d_in[4];
    const float* wk    = (const float*)d_in[5];
    const float* bk    = (const float*)d_in[6];
    const float* wv    = (const float*)d_in[7];
    const float* bv    = (const float*)d_in[8];
    const float* wo    = (const float*)d_in[9];
    const float* bo    = (const float*)d_in[10];

    char* ws = (char*)d_ws;
    const size_t MB = 1024 * 1024;
    unsigned short* qB  = (unsigned short*)(ws);             // bf16 [4096,1024] 8 MB (dead after gemm_qkv)
    unsigned short* kB  = (unsigned short*)(ws + 8 * MB);
    unsigned short* vB  = (unsigned short*)(ws + 16 * MB);
    unsigned short* wqB = (unsigned short*)(ws + 24 * MB);   // bf16 [1024,1024] 2 MB
    unsigned short* wkB = (unsigned short*)(ws + 26 * MB);
    unsigned short* wvB = (unsigned short*)(ws + 28 * MB);
    unsigned short* woB = (unsigned short*)(ws + 30 * MB);
    unsigned short* Qh  = (unsigned short*)(ws + 32 * MB);   // bf16 [B,H,S,DK] 8 MB
    unsigned short* Kh  = (unsigned short*)(ws + 40 * MB);
    unsigned short* Vt  = (unsigned short*)(ws + 48 * MB);   // bf16 [B,H,DK,VSTR] ~8.9 MB
    unsigned short* Xb  = qB;                                // bf16 [B,S,D] reuses qB region

    cast3<<<dim3(4096, 3), 256, 0, stream>>>(query, key, value, qB, kB, vB);
    cast4w<<<dim3(1024, 4), 256, 0, stream>>>(wq, wk, wv, wo, wqB, wkB, wvB, woB);

    gemm_qkv<<<1536, 256, 0, stream>>>(qB, kB, vB, wqB, wkB, wvB, bq, bk, bv, Qh, Kh, Vt);

    attn_mfma<<<1024, 256, 0, stream>>>(Qh, Kh, Vt, Xb);

    gemm_out<<<512, 256, 0, stream>>>(Xb, woB, bo, (float*)d_out);
}

// Round 9
// 227.203 us; speedup vs baseline: 1.3963x; 1.1016x over previous
//
#include <hip/hip_runtime.h>
#include <math.h>

#define BB 2
#define SS 2048
#define DD 1024
#define HH 16
#define DKK 64
#define MM (BB * SS) /* 4096 */
#define KK DD        /* GEMM K = 1024 */
#define VSTR 2176    /* Vt row stride in shorts (4352 B) — breaks 4 KB channel aliasing */

typedef __attribute__((ext_vector_type(8))) short short8;
typedef __attribute__((ext_vector_type(4))) float floatx4;

__device__ inline unsigned short f2bf(float x) {
    unsigned int u = __float_as_uint(x);
    u += 0x7fffu + ((u >> 16) & 1u);   // round to nearest even
    return (unsigned short)(u >> 16);
}

// pack two fp32 -> bf16x2 dword (truncating): lo from a, hi from b
__device__ inline unsigned int pkbf(float a, float b) {
    return (__float_as_uint(b) & 0xffff0000u) | (__float_as_uint(a) >> 16);
}

__device__ inline void cast4f(const float* __restrict__ in, unsigned short* __restrict__ out, int i) {
    const float4 v = *(const float4*)(in + i);
    unsigned long long pk = (unsigned long long)f2bf(v.x)
                          | ((unsigned long long)f2bf(v.y) << 16)
                          | ((unsigned long long)f2bf(v.z) << 32)
                          | ((unsigned long long)f2bf(v.w) << 48);
    *(unsigned long long*)(out + i) = pk;
}

// single fused cast dispatch: blocks 0..12287 -> q/k/v (4096 each); 12288..16383 -> weights (1024 each)
__global__ __launch_bounds__(256) void cast_all(const float* __restrict__ q, const float* __restrict__ k,
                                                const float* __restrict__ v,
                                                const float* __restrict__ wq, const float* __restrict__ wk,
                                                const float* __restrict__ wv, const float* __restrict__ wo,
                                                unsigned short* __restrict__ oq, unsigned short* __restrict__ ok,
                                                unsigned short* __restrict__ ov,
                                                unsigned short* __restrict__ owq, unsigned short* __restrict__ owk,
                                                unsigned short* __restrict__ owv, unsigned short* __restrict__ owo) {
    const int blk = blockIdx.x;
    const float* in;
    unsigned short* out;
    int idx;
    if (blk < 12288) {
        const int w = blk >> 12;            // /4096
        idx = blk & 4095;
        in  = (w == 0) ? q : (w == 1) ? k : v;
        out = (w == 0) ? oq : (w == 1) ? ok : ov;
    } else {
        const int w = (blk - 12288) >> 10;  // /1024
        idx = (blk - 12288) & 1023;
        in  = (w == 0) ? wq : (w == 1) ? wk : (w == 2) ? wv : wo;
        out = (w == 0) ? owq : (w == 1) ? owk : (w == 2) ? owv : owo;
    }
    cast4f(in, out, (idx * 256 + threadIdx.x) * 4);
}

#define GLDS(gp, lp) __builtin_amdgcn_global_load_lds( \
    (const __attribute__((address_space(1))) void*)(gp), \
    (__attribute__((address_space(3))) void*)(lp), 16, 0, 0)

// ---------- 64(M)x128(N) tile GEMM body (used by gemm_out) ----------
__device__ __forceinline__ void gemm_body(const unsigned short* __restrict__ A,
                                          const unsigned short* __restrict__ W,
                                          const float* __restrict__ bias,
                                          void* __restrict__ Cout, int mode, int blk,
                                          unsigned short* As, unsigned short* Bs) {
    const int t    = threadIdx.x;
    const int lane = t & 63;
    const int wave = t >> 6;
    const int col  = lane & 15;
    const int quad = lane >> 4;

    const int m0  = (blk & 63) * 64;
    const int n0  = (blk >> 6) * 128;
    const int wm0 = (wave & 1) * 32;
    const int wn0 = (wave >> 1) * 64;

    const int sw = ((t & 3) ^ ((t >> 3) & 3)) * 8;
    const size_t arow = (size_t)(m0 + (t >> 2)) * KK + sw;
    const size_t brow = (size_t)(n0 + (t >> 2)) * KK + sw;
    const int rseg = (quad ^ ((col >> 1) & 3)) * 8;

    floatx4 acc[2][4] = {};

    GLDS(A + arow,           &As[(t >> 2) * 32 + sw]);
    GLDS(W + brow,           &Bs[(t >> 2) * 32 + sw]);
    GLDS(W + brow + 64 * KK, &Bs[(64 + (t >> 2)) * 32 + sw]);

    int cur = 0;
    for (int kb = 0; kb < KK / 32; ++kb) {
        __syncthreads();

        if (kb + 1 < KK / 32) {
            const int k0 = (kb + 1) * 32;
            const int nx = cur ^ 1;
            GLDS(A + arow + k0,           &As[nx * 64 * 32 + (t >> 2) * 32 + sw]);
            GLDS(W + brow + k0,           &Bs[nx * 128 * 32 + (t >> 2) * 32 + sw]);
            GLDS(W + brow + k0 + 64 * KK, &Bs[nx * 128 * 32 + (64 + (t >> 2)) * 32 + sw]);
        }

        const unsigned short* Ab = &As[cur * 64 * 32];
        const unsigned short* Bb = &Bs[cur * 128 * 32];
        short8 a[2], b[4];
        #pragma unroll
        for (int i = 0; i < 2; ++i)
            a[i] = *(const short8*)(Ab + (wm0 + i * 16 + col) * 32 + rseg);
        #pragma unroll
        for (int j = 0; j < 4; ++j)
            b[j] = *(const short8*)(Bb + (wn0 + j * 16 + col) * 32 + rseg);

        #pragma unroll
        for (int i = 0; i < 2; ++i)
            #pragma unroll
            for (int j = 0; j < 4; ++j)
                acc[i][j] = __builtin_amdgcn_mfma_f32_16x16x32_bf16(a[i], b[j], acc[i][j], 0, 0, 0);

        cur ^= 1;
    }

    #pragma unroll
    for (int i = 0; i < 2; ++i) {
        #pragma unroll
        for (int j = 0; j < 4; ++j) {
            const int n  = n0 + wn0 + j * 16 + col;
            const float bv = bias[n];
            #pragma unroll
            for (int r = 0; r < 4; ++r) {
                const int m = m0 + wm0 + i * 16 + quad * 4 + r;
                const float v = acc[i][j][r] + bv;
                ((float*)Cout)[(size_t)m * DD + n] = v;
            }
        }
    }
    (void)mode;
}

// ---------- fused Q/K/V projections: 128x128 tiles, 768 blocks = 3 blocks/CU ----------
__global__ __launch_bounds__(256) void gemm_qkv(const unsigned short* __restrict__ qB,
                                                const unsigned short* __restrict__ kB,
                                                const unsigned short* __restrict__ vB,
                                                const unsigned short* __restrict__ wqB,
                                                const unsigned short* __restrict__ wkB,
                                                const unsigned short* __restrict__ wvB,
                                                const float* __restrict__ bq,
                                                const float* __restrict__ bk,
                                                const float* __restrict__ bv,
                                                unsigned short* __restrict__ Qh,
                                                unsigned short* __restrict__ Kh,
                                                unsigned short* __restrict__ Vt) {
    __shared__ __align__(16) unsigned short As[2 * 128 * 32];
    __shared__ __align__(16) unsigned short Bs[2 * 128 * 32];

    const int which = blockIdx.x >> 8;       // 0=Q 1=K 2=V
    const int blk   = blockIdx.x & 255;
    const unsigned short* A = (which == 0) ? qB : (which == 1) ? kB : vB;
    const unsigned short* W = (which == 0) ? wqB : (which == 1) ? wkB : wvB;
    const float* bias       = (which == 0) ? bq : (which == 1) ? bk : bv;

    const int t    = threadIdx.x;
    const int lane = t & 63;
    const int wave = t >> 6;
    const int col  = lane & 15;
    const int quad = lane >> 4;

    const int m0  = (blk & 31) * 128;
    const int n0  = (blk >> 5) * 128;
    const int wm0 = (wave & 1) * 64;
    const int wn0 = (wave >> 1) * 64;

    const int sw = ((t & 3) ^ ((t >> 3) & 3)) * 8;
    const size_t arow = (size_t)(m0 + (t >> 2)) * KK + sw;
    const size_t brow = (size_t)(n0 + (t >> 2)) * KK + sw;
    const int rseg = (quad ^ ((col >> 1) & 3)) * 8;

    floatx4 acc[4][4] = {};

    GLDS(A + arow,           &As[(t >> 2) * 32 + sw]);
    GLDS(A + arow + 64 * KK, &As[(64 + (t >> 2)) * 32 + sw]);
    GLDS(W + brow,           &Bs[(t >> 2) * 32 + sw]);
    GLDS(W + brow + 64 * KK, &Bs[(64 + (t >> 2)) * 32 + sw]);

    int cur = 0;
    for (int kb = 0; kb < KK / 32; ++kb) {
        __syncthreads();

        if (kb + 1 < KK / 32) {
            const int k0 = (kb + 1) * 32;
            const int nx = cur ^ 1;
            GLDS(A + arow + k0,           &As[nx * 128 * 32 + (t >> 2) * 32 + sw]);
            GLDS(A + arow + k0 + 64 * KK, &As[nx * 128 * 32 + (64 + (t >> 2)) * 32 + sw]);
            GLDS(W + brow + k0,           &Bs[nx * 128 * 32 + (t >> 2) * 32 + sw]);
            GLDS(W + brow + k0 + 64 * KK, &Bs[nx * 128 * 32 + (64 + (t >> 2)) * 32 + sw]);
        }

        const unsigned short* Ab = &As[cur * 128 * 32];
        const unsigned short* Bb = &Bs[cur * 128 * 32];
        short8 a[4], b[4];
        #pragma unroll
        for (int i = 0; i < 4; ++i)
            a[i] = *(const short8*)(Ab + (wm0 + i * 16 + col) * 32 + rseg);
        #pragma unroll
        for (int j = 0; j < 4; ++j)
            b[j] = *(const short8*)(Bb + (wn0 + j * 16 + col) * 32 + rseg);

        #pragma unroll
        for (int i = 0; i < 4; ++i)
            #pragma unroll
            for (int j = 0; j < 4; ++j)
                acc[i][j] = __builtin_amdgcn_mfma_f32_16x16x32_bf16(a[i], b[j], acc[i][j], 0, 0, 0);

        cur ^= 1;
    }

    #pragma unroll
    for (int i = 0; i < 4; ++i) {
        #pragma unroll
        for (int j = 0; j < 4; ++j) {
            const int n  = n0 + wn0 + j * 16 + col;
            const float bv = bias[n];
            const int h = n / DKK, dk = n % DKK;
            #pragma unroll
            for (int r = 0; r < 4; ++r) {
                const int m = m0 + wm0 + i * 16 + quad * 4 + r;
                const int bdx = m / SS, s = m % SS;
                const float v = acc[i][j][r] + bv;
                if (which != 2) {
                    unsigned short* O = (which == 0) ? Qh : Kh;
                    O[(((size_t)(bdx * HH + h)) * SS + s) * DKK + dk] = f2bf(v);
                } else {
                    Vt[(((size_t)(bdx * HH + h)) * DKK + dk) * VSTR + s] = f2bf(v);
                }
            }
        }
    }
}

__global__ __launch_bounds__(256) void gemm_out(const unsigned short* __restrict__ A,
                                                const unsigned short* __restrict__ W,
                                                const float* __restrict__ bias,
                                                float* __restrict__ C) {
    __shared__ __align__(16) unsigned short As[2 * 64 * 32];
    __shared__ __align__(16) unsigned short Bs[2 * 128 * 32];
    gemm_body(A, W, bias, C, 2, blockIdx.x, As, Bs);
}

// ---------- attention ----------
#define C1 0.18033688011112042f   /* 0.125 * log2(e) */
#define C2 11.541560327111707f    /* 8 * log2(e)     */
#define MFMA __builtin_amdgcn_mfma_f32_16x16x32_bf16

// S^T-oriented GEMM-style flash attention.
// One block = 64 consecutive queries (4 waves x 16 q). K/V staged block-wide into
// dbuf LDS (BK=64 keys/barrier) via global_load_lds, XOR-swizzled segs.
// S^T = K*Q^T puts 4 consecutive keys per lane -> P^T pack = 2 ds_write_b64,
// PV = V^T * P^T with one b128 P read; output O^T packs to b64 stores.
__global__ __launch_bounds__(256) void attn_mfma(const unsigned short* __restrict__ Qh,
                                                 const unsigned short* __restrict__ Kh,
                                                 const unsigned short* __restrict__ Vt,
                                                 unsigned short* __restrict__ X) {
    __shared__ __align__(16) unsigned short Ks[2][64 * 64];   // [key][dim], swizzled segs
    __shared__ __align__(16) unsigned short Vs[2][64 * 64];   // [dim][key], swizzled segs
    __shared__ __align__(16) unsigned short Plds[4][16 * 40]; // [q][key], stride 40 shorts

    const int t    = threadIdx.x;
    const int lane = t & 63;
    const int wave = t >> 6;
    const int col  = lane & 15;
    const int quad = lane >> 4;

    // xcd = lin&7 (heads {x,x+8,x+16,x+24} per xcd); chunks descending (longest first)
    const int lin = blockIdx.x;                    // 0..1023
    const int bh  = (lin & 7) + 8 * ((lin >> 3) & 3);
    const int c   = 31 - (lin >> 5);               // chunk of 64 queries
    const int b   = bh / HH, h = bh % HH;

    const unsigned short* Kb = Kh + (size_t)bh * SS * DKK;
    const unsigned short* Vb = Vt + (size_t)bh * DKK * VSTR;

    // staging positions p0 = t, p1 = t+256: row = p>>3, phys seg = p&7,
    // source seg = (p&7) ^ (row&7)  (same swizzle for K and V)
    const int r0  = t >> 3;
    const int r1  = (t + 256) >> 3;
    const int sg0 = ((t & 7) ^ (r0 & 7)) * 8;
    const int sg1 = ((t & 7) ^ (r1 & 7)) * 8;

    const int q0 = c * 64 + wave * 16;
    unsigned short* Pw = &Plds[wave][0];

    const unsigned short* Qb = Qh + ((size_t)bh * SS + q0) * DKK;
    const short8 qa0 = *(const short8*)(Qb + (size_t)col * DKK + quad * 8);
    const short8 qa1 = *(const short8*)(Qb + (size_t)col * DKK + 32 + quad * 8);

    floatx4 o0 = {0.f, 0.f, 0.f, 0.f}, o1 = o0, o2 = o0, o3 = o0;
    float lp = 0.f;

    const int nst = c + 1;                          // 64-key steps

    // fragment read seg offsets (must match staging swizzle)
    const int ksA = ((quad)      ^ (col & 7)) * 8;  // dims/keys seg quad
    const int ksB = ((quad | 4)  ^ (col & 7)) * 8;  // seg quad+4

    // prologue: stage step 0 into buf 0
    GLDS(Kb + (size_t)r0 * DKK + sg0,  &Ks[0][t * 8]);
    GLDS(Kb + (size_t)r1 * DKK + sg1,  &Ks[0][(t + 256) * 8]);
    GLDS(Vb + (size_t)r0 * VSTR + sg0, &Vs[0][t * 8]);
    GLDS(Vb + (size_t)r1 * VSTR + sg1, &Vs[0][(t + 256) * 8]);

    int cur = 0;
    for (int kb = 0; kb < nst; ++kb) {
        __syncthreads();

        if (kb + 1 < nst) {
            const int jn = (kb + 1) * 64;
            const int nx = cur ^ 1;
            GLDS(Kb + (size_t)(jn + r0) * DKK + sg0,  &Ks[nx][t * 8]);
            GLDS(Kb + (size_t)(jn + r1) * DKK + sg1,  &Ks[nx][(t + 256) * 8]);
            GLDS(Vb + (size_t)r0 * VSTR + jn + sg0,   &Vs[nx][t * 8]);
            GLDS(Vb + (size_t)r1 * VSTR + jn + sg1,   &Vs[nx][(t + 256) * 8]);
        }

        const unsigned short* Kp = &Ks[cur][0];
        const unsigned short* Vp = &Vs[cur][0];

        #pragma unroll
        for (int hh = 0; hh < 2; ++hh) {
            const int j0 = kb * 64 + hh * 32;
            if (j0 < q0 + 16) {
                // S^T tiles: keys j0+0..15 (t0) and j0+16..31 (t1); A=K rows, B=Q
                const short8 k0 = *(const short8*)(Kp + (hh * 32 + col) * 64 + ksA);
                const short8 k1 = *(const short8*)(Kp + (hh * 32 + col) * 64 + ksB);
                const short8 k2 = *(const short8*)(Kp + (hh * 32 + col + 16) * 64 + ksA);
                const short8 k3 = *(const short8*)(Kp + (hh * 32 + col + 16) * 64 + ksB);

                floatx4 t0 = {0.f, 0.f, 0.f, 0.f}, t1 = t0;
                t0 = MFMA(k0, qa0, t0, 0, 0, 0);
                t0 = MFMA(k1, qa1, t0, 0, 0, 0);
                t1 = MFMA(k2, qa0, t1, 0, 0, 0);
                t1 = MFMA(k3, qa1, t1, 0, 0, 0);

                // lane (col=q, quad) holds keys j0+quad*4+r (t0), j0+16+quad*4+r (t1)
                float p[8];
                if (j0 + 31 > q0) {   // diagonal: per-lane mask
                    const int lim = q0 + col - j0;   // keys rel <= lim pass
                    #pragma unroll
                    for (int r = 0; r < 4; ++r) {
                        p[r]     = (quad * 4 + r      <= lim) ? __builtin_exp2f(fmaf(t0[r], C1, -C2)) : 0.f;
                        p[4 + r] = (16 + quad * 4 + r <= lim) ? __builtin_exp2f(fmaf(t1[r], C1, -C2)) : 0.f;
                    }
                } else {
                    #pragma unroll
                    for (int r = 0; r < 4; ++r) {
                        p[r]     = __builtin_exp2f(fmaf(t0[r], C1, -C2));
                        p[4 + r] = __builtin_exp2f(fmaf(t1[r], C1, -C2));
                    }
                }
                lp += (p[0] + p[1]) + (p[2] + p[3]) + (p[4] + p[5]) + (p[6] + p[7]);

                // P^T -> LDS: keys rel quad*4..+3 and 16+quad*4..+3 of row q=col
                uint2 w0 = { pkbf(p[0], p[1]), pkbf(p[2], p[3]) };
                uint2 w1 = { pkbf(p[4], p[5]), pkbf(p[6], p[7]) };
                *(uint2*)(Pw + col * 40 + quad * 4)      = w0;
                *(uint2*)(Pw + col * 40 + 16 + quad * 4) = w1;

                // PV: A = V^T (dim rows), B = P^T (one b128, keys quad*8..+7 of q=col)
                const short8 pb = *(const short8*)(Pw + col * 40 + quad * 8);
                const int vs = hh ? ksB : ksA;    // V seg (4*hh+quad)^(col&7)
                const short8 v0 = *(const short8*)(Vp + (col)      * 64 + vs);
                const short8 v1 = *(const short8*)(Vp + (col + 16) * 64 + vs);
                const short8 v2 = *(const short8*)(Vp + (col + 32) * 64 + vs);
                const short8 v3 = *(const short8*)(Vp + (col + 48) * 64 + vs);
                o0 = MFMA(v0, pb, o0, 0, 0, 0);
                o1 = MFMA(v1, pb, o1, 0, 0, 0);
                o2 = MFMA(v2, pb, o2, 0, 0, 0);
                o3 = MFMA(v3, pb, o3, 0, 0, 0);
            }
        }

        cur ^= 1;
    }

    // combine l across quads (lanes col, col+16, col+32, col+48 share q=col)
    lp += __shfl_xor(lp, 16, 64);
    lp += __shfl_xor(lp, 32, 64);
    const float li = 1.f / lp;

    // O^T: lane (col=q, quad) holds dims 16m + quad*4 + r -> 4 packed b64 stores
    unsigned short* Xp = X + ((size_t)(b * SS + q0 + col)) * DD + h * DKK + quad * 4;
    {
        uint2 w;
        w.x = (unsigned int)f2bf(o0[0] * li) | ((unsigned int)f2bf(o0[1] * li) << 16);
        w.y = (unsigned int)f2bf(o0[2] * li) | ((unsigned int)f2bf(o0[3] * li) << 16);
        *(uint2*)(Xp + 0) = w;
        w.x = (unsigned int)f2bf(o1[0] * li) | ((unsigned int)f2bf(o1[1] * li) << 16);
        w.y = (unsigned int)f2bf(o1[2] * li) | ((unsigned int)f2bf(o1[3] * li) << 16);
        *(uint2*)(Xp + 16) = w;
        w.x = (unsigned int)f2bf(o2[0] * li) | ((unsigned int)f2bf(o2[1] * li) << 16);
        w.y = (unsigned int)f2bf(o2[2] * li) | ((unsigned int)f2bf(o2[3] * li) << 16);
        *(uint2*)(Xp + 32) = w;
        w.x = (unsigned int)f2bf(o3[0] * li) | ((unsigned int)f2bf(o3[1] * li) << 16);
        w.y = (unsigned int)f2bf(o3[2] * li) | ((unsigned int)f2bf(o3[3] * li) << 16);
        *(uint2*)(Xp + 48) = w;
    }
}

extern "C" void kernel_launch(void* const* d_in, const int* in_sizes, int n_in,
                              void* d_out, int out_size, void* d_ws, size_t ws_size,
                              hipStream_t stream) {
    const float* query = (const float*)d_in[0];
    const float* key   = (const float*)d_in[1];
    const float* value = (const float*)d_in[2];
    const float* wq    = (const float*)d_in[3];
    const float* bq    = (const float*)d_in[4];
    const float* wk    = (const float*)d_in[5];
    const float* bk    = (const float*)d_in[6];
    const float* wv    = (const float*)d_in[7];
    const float* bv    = (const float*)d_in[8];
    const float* wo    = (const float*)d_in[9];
    const float* bo    = (const float*)d_in[10];

    char* ws = (char*)d_ws;
    const size_t MB = 1024 * 1024;
    unsigned short* qB  = (unsigned short*)(ws);             // bf16 [4096,1024] 8 MB (dead after gemm_qkv)
    unsigned short* kB  = (unsigned short*)(ws + 8 * MB);
    unsigned short* vB  = (unsigned short*)(ws + 16 * MB);
    unsigned short* wqB = (unsigned short*)(ws + 24 * MB);   // bf16 [1024,1024] 2 MB
    unsigned short* wkB = (unsigned short*)(ws + 26 * MB);
    unsigned short* wvB = (unsigned short*)(ws + 28 * MB);
    unsigned short* woB = (unsigned short*)(ws + 30 * MB);
    unsigned short* Qh  = (unsigned short*)(ws + 32 * MB);   // bf16 [B,H,S,DK] 8 MB
    unsigned short* Kh  = (unsigned short*)(ws + 40 * MB);
    unsigned short* Vt  = (unsigned short*)(ws + 48 * MB);   // bf16 [B,H,DK,VSTR] ~8.9 MB
    unsigned short* Xb  = qB;                                // bf16 [B,S,D] reuses qB region

    cast_all<<<16384, 256, 0, stream>>>(query, key, value, wq, wk, wv, wo,
                                        qB, kB, vB, wqB, wkB, wvB, woB);

    gemm_qkv<<<768, 256, 0, stream>>>(qB, kB, vB, wqB, wkB, wvB, bq, bk, bv, Qh, Kh, Vt);

    attn_mfma<<<1024, 256, 0, stream>>>(Qh, Kh, Vt, Xb);

    gemm_out<<<512, 256, 0, stream>>>(Xb, woB, bo, (float*)d_out);
}